// Round 2
// baseline (377.932 us; speedup 1.0000x reference)
//
#include <hip/hip_runtime.h>

#define TOKENS 65536
#define DIM 64
#define NCODE 1024
#define CHUNK 256

#define OUT_IDX_OFF ((size_t)TOKENS * DIM)          // 4194304
#define OUT_LOSS_OFF (OUT_IDX_OFF + TOKENS)         // 4259840

// ---------------------------------------------------------------------------
// Bitwise emulation of numpy float32 kernels (the harness ref is "np", f32).
// All ops use explicit rounding intrinsics / contract(off) so hipcc's default
// -ffp-contract=fast cannot fuse or reassociate.
// ---------------------------------------------------------------------------

// np.sum(x**2) over 64 contiguous f32: numpy pairwise_sum n<=PW_BLOCKSIZE path:
// 8 accumulators stride-8 (sequential adds), combine ((r0+r1)+(r2+r3))+((r4+r5)+(r6+r7)).
// x**2 is a materialized temp -> plain rounded mul per element, plain adds (no FMA).
__device__ __forceinline__ float np_sumsq64(const float* __restrict__ x) {
#pragma clang fp contract(off)
    float r[8];
#pragma unroll
    for (int j = 0; j < 8; ++j) r[j] = x[j] * x[j];
#pragma unroll
    for (int i = 8; i < 64; i += 8) {
#pragma unroll
        for (int j = 0; j < 8; ++j) {
            float sq = x[i + j] * x[i + j];
            r[j] = r[j] + sq;
        }
    }
    return ((r[0] + r[1]) + (r[2] + r[3])) + ((r[4] + r[5]) + (r[6] + r[7]));
}

// np.einsum('btd,kd->btk') inner dot, count=64, both contiguous, f32:
// npyv contig_contig_outstride0_two, AVX512 (vstep=16, vstepx4=64 -> 1 iter):
//   per lane j: fma(a0,b0, fma(a1,b1, fma(a2,b2, fma(a3,b3, 0))))
//   (a_i = elements [16i,16i+16); innermost = elements 48..63)
// then npyv_sum_f32 = halving tree over 16 lanes.
__device__ __forceinline__ float np_dot64(const float* __restrict__ a,
                                          const float* __restrict__ b) {
#pragma clang fp contract(off)
    float l[16];
#pragma unroll
    for (int j = 0; j < 16; ++j) {
        float acc = a[48 + j] * b[48 + j];            // fma(a3,b3,+0) == rounded mul
        acc = __fmaf_rn(a[32 + j], b[32 + j], acc);
        acc = __fmaf_rn(a[16 + j], b[16 + j], acc);
        acc = __fmaf_rn(a[j],      b[j],      acc);
        l[j] = acc;
    }
#pragma unroll
    for (int j = 0; j < 8; ++j) l[j] = l[j] + l[j + 8];
#pragma unroll
    for (int j = 0; j < 4; ++j) l[j] = l[j] + l[j + 4];
    l[0] = l[0] + l[2];
    l[1] = l[1] + l[3];
    return l[0] + l[1];
}

__global__ __launch_bounds__(256) void vq_bnorm(const float* __restrict__ cb,
                                                float* __restrict__ bnorm) {
    int k = blockIdx.x * 256 + threadIdx.x;
    bnorm[k] = np_sumsq64(cb + (size_t)k * DIM);
}

__global__ __launch_bounds__(256) void vq_main(
    const float* __restrict__ z, const float* __restrict__ cb,
    float* __restrict__ out, const float* __restrict__ bnorm,
    double* __restrict__ loss_sum) {
    __shared__ float lds_c[CHUNK * DIM];   // 64 KB
    __shared__ float lds_b[CHUNK];

    const int tid = threadIdx.x;
    const int t = blockIdx.x * 256 + tid;

    // token vector in registers
    float zr[DIM];
    {
        const float4* z4 = (const float4*)(z + (size_t)t * DIM);
#pragma unroll
        for (int j = 0; j < 16; ++j) {
            float4 v = z4[j];
            zr[4 * j + 0] = v.x; zr[4 * j + 1] = v.y;
            zr[4 * j + 2] = v.z; zr[4 * j + 3] = v.w;
        }
    }

    const float s_z = np_sumsq64(zr);   // numpy-bitwise ||z||^2

    float m1 = 3.0e38f;
    int best = 0;

    for (int c0 = 0; c0 < NCODE; c0 += CHUNK) {
        __syncthreads();
        {
            const float4* src = (const float4*)(cb + (size_t)c0 * DIM);
            float4* dst = (float4*)lds_c;
#pragma unroll
            for (int j = 0; j < (CHUNK * DIM / 4) / 256; ++j)
                dst[tid + 256 * j] = src[tid + 256 * j];
            lds_b[tid] = bnorm[c0 + tid];
        }
        __syncthreads();
        for (int kk = 0; kk < CHUNK; ++kk) {
            // pull the code row into registers (broadcast LDS reads)
            float cr[DIM];
            {
                const float4* c4 = (const float4*)(lds_c + kk * DIM);
#pragma unroll
                for (int j = 0; j < 16; ++j) {
                    float4 v = c4[j];
                    cr[4 * j + 0] = v.x; cr[4 * j + 1] = v.y;
                    cr[4 * j + 2] = v.z; cr[4 * j + 3] = v.w;
                }
            }
            float e = np_dot64(zr, cr);
            float d;
            {
#pragma clang fp contract(off)
                float t1 = s_z + lds_b[kk];   // fl(s_z + s_c)
                float m = 2.0f * e;           // exact (x2)
                d = t1 - m;                   // fl(t1 - 2e)
            }
            int k = c0 + kk;
            if (d < m1) { m1 = d; best = k; }   // strict <: first occurrence, == np.argmin
        }
    }

    // epilogue: z_q_st = fl(z + fl(z_q - z)), loss via f64 atomics
    float loss_t = 0.0f;
    {
        const float4* cb4 = (const float4*)(cb + (size_t)best * DIM);
        float4* o4 = (float4*)(out + (size_t)t * DIM);
#pragma unroll
        for (int j = 0; j < 16; ++j) {
#pragma clang fp contract(off)
            float4 c = cb4[j];
            float d0 = c.x - zr[4 * j + 0];
            float d1 = c.y - zr[4 * j + 1];
            float d2 = c.z - zr[4 * j + 2];
            float d3 = c.w - zr[4 * j + 3];
            float4 o;
            o.x = zr[4 * j + 0] + d0;
            o.y = zr[4 * j + 1] + d1;
            o.z = zr[4 * j + 2] + d2;
            o.w = zr[4 * j + 3] + d3;
            o4[j] = o;
            loss_t = __fmaf_rn(d0, d0, loss_t);
            loss_t = __fmaf_rn(d1, d1, loss_t);
            loss_t = __fmaf_rn(d2, d2, loss_t);
            loss_t = __fmaf_rn(d3, d3, loss_t);
        }
    }
    out[OUT_IDX_OFF + t] = (float)best;

#pragma unroll
    for (int off = 32; off > 0; off >>= 1)
        loss_t += __shfl_down(loss_t, off);
    if ((tid & 63) == 0)
        atomicAdd(loss_sum, (double)loss_t);
}

__global__ void vq_loss_final(const double* __restrict__ loss_sum,
                              float* __restrict__ out) {
    // loss = mean((zq-z)^2) + BETA*mean((zq-z)^2), BETA=1 -> 2*mean
    out[OUT_LOSS_OFF] = (float)(2.0 * (*loss_sum) / (double)((size_t)TOKENS * DIM));
}

extern "C" void kernel_launch(void* const* d_in, const int* in_sizes, int n_in,
                              void* d_out, int out_size, void* d_ws, size_t ws_size,
                              hipStream_t stream) {
    const float* z  = (const float*)d_in[0];   // [8,8192,64] f32
    const float* cb = (const float*)d_in[1];   // [1024,64] f32
    float* out = (float*)d_out;

    double* loss_sum = (double*)d_ws;
    float* bnorm = (float*)((char*)d_ws + 16);

    hipMemsetAsync(d_ws, 0, 16, stream);
    vq_bnorm<<<dim3(NCODE / 256), dim3(256), 0, stream>>>(cb, bnorm);
    vq_main<<<dim3(TOKENS / 256), dim3(256), 0, stream>>>(z, cb, out, bnorm, loss_sum);
    vq_loss_final<<<dim3(1), dim3(1), 0, stream>>>(loss_sum, out);
}